// Round 2
// baseline (173.243 us; speedup 1.0000x reference)
//
#include <hip/hip_runtime.h>

namespace {

constexpr int B = 128, N = 2048, E = 32768;
constexpr int LOG2N = 11, LOG2E = 15;
constexpr int QE = E / 4;          // edges per quarter block = 8192
constexpr int LOG2QE = 13;

// ws layout (bytes)
constexpr size_t OFF_H0 = 0;                     // B*N float4 = 4 MB
constexpr size_t OFF_H1 = 4u * 1024 * 1024;      // B*N float4 = 4 MB
constexpr size_t OFF_S8 = 8u * 1024 * 1024;      // B*4 quarters * QE int2 = 32 MB
constexpr size_t OFF_RP = 40u * 1024 * 1024;     // B*4*(N+1) int ~ 4.2 MB

// One block per (batch, quarter). Builds a per-quarter CSR of (src, dt)
// records entirely in LDS, then streams it out coalesced.
__global__ __launch_bounds__(1024) void sort_kernel(const int* __restrict__ edge_index,
                                                    const float* __restrict__ edge_time,
                                                    const float* __restrict__ timestamp,
                                                    int2* __restrict__ sorted8,
                                                    int* __restrict__ row_ptr) {
  __shared__ int  cnt[N];        // 8 KB: counts -> cursors
  __shared__ int  wsum[16];
  __shared__ int2 rec[QE];       // 64 KB: local CSR records
  int blk = blockIdx.x, b = blk >> 2, q = blk & 3, t = threadIdx.x;

  cnt[t] = 0; cnt[t + 1024] = 0;
  __syncthreads();

  const int* src_arr = edge_index + (((size_t)(2 * b)) << LOG2E) + q * QE;
  const int* dst_arr = edge_index + (((size_t)(2 * b + 1)) << LOG2E) + q * QE;
  const float* et    = edge_time + (((size_t)b) << LOG2E) + q * QE;
  float ts = timestamp[b];

  // hist
  for (int e = t; e < QE; e += 1024) atomicAdd(&cnt[dst_arr[e]], 1);
  __syncthreads();

  // exclusive scan of 2048 counts (2 per thread): wave shuffle scan +
  // single 16-partial scan. 2 barriers total.
  int i0 = 2 * t, i1 = 2 * t + 1;
  int l0 = cnt[i0], l1 = cnt[i1];
  int sum = l0 + l1;
  int lane = t & 63, wid = t >> 6;
  int incl = sum;
#pragma unroll
  for (int d = 1; d < 64; d <<= 1) {
    int v = __shfl_up(incl, d, 64);
    if (lane >= d) incl += v;
  }
  if (lane == 63) wsum[wid] = incl;
  __syncthreads();
  if (t < 16) {
    int v = wsum[t];
    int inc = v;
#pragma unroll
    for (int d = 1; d < 16; d <<= 1) {
      int u = __shfl_up(inc, d, 16);
      if (t >= d) inc += u;
    }
    wsum[t] = inc - v;  // exclusive wave offset
  }
  __syncthreads();
  int run = wsum[wid] + (incl - sum);
  int run2 = run + l0;
  int* rp = row_ptr + (size_t)blk * (N + 1);
  rp[i0] = run;
  rp[i1] = run2;
  if (t == 1023) rp[N] = QE;
  cnt[i0] = run;   // becomes cursor
  cnt[i1] = run2;
  __syncthreads();

  // scatter into LDS CSR
  for (int e = t; e < QE; e += 1024) {
    int dst = dst_arr[e];
    int src = src_arr[e];
    float dt = ts - et[e];
    int pos = atomicAdd(&cnt[dst], 1);
    rec[pos] = make_int2(src, __float_as_int(dt));
  }
  __syncthreads();

  // coalesced stream-out (int4 = 2 records)
  const int4* rec4 = (const int4*)rec;
  int4* out4 = (int4*)(sorted8 + (((size_t)blk) << LOG2QE));
#pragma unroll
  for (int i = t; i < QE / 2; i += 1024) out4[i] = rec4[i];
}

// R7 layer kernel:
//  - NO online max: logits are O(+-10) for this model (unit-normal-ish q,k,
//    2-dim dots), so p=exp(l) cannot overflow fp32 and attn = sum(p*v)/sum(p)
//    is mathematically identical to the max-subtracted reference. Removes the
//    serial m/s rescale chain -> body is pure feed-forward FMA accumulates.
//  - 2 records per iteration (slots A/B) with independent accumulator sets,
//    combined at the end. Wave-max trip count ~27 -> ~14; 2x load overlap.
//    Slot A is always valid inside the loop; slot B's tail slot is killed by
//    p:=0 (dt sanitized first so no 0*NaN can reach the accumulators).
//  - log2(e)*rsqrt(2) folded into q; 1/(2pi) folded into time weights; raw
//    v_exp_f32 / v_cos_f32 via asm (args < 1 revolution, inside hw domain).
__global__ __launch_bounds__(1024) void layer_kernel(const float4* __restrict__ h_in,
                                                     float4* __restrict__ h_out,
                                                     const int* __restrict__ row_ptr,
                                                     const int2* __restrict__ sorted8,
                                                     const float* __restrict__ tw,
                                                     const float* __restrict__ tb,
                                                     const float* __restrict__ Wq,
                                                     const float* __restrict__ Wk,
                                                     const float* __restrict__ Wv,
                                                     const float* __restrict__ Wo,
                                                     const float* __restrict__ bo) {
  __shared__ float4 lh[N];  // 32 KB
  int blk = blockIdx.x, b = blk >> 1, half = blk & 1, t = threadIdx.x;

  const float4* hb = h_in + (((size_t)b) << LOG2N);
  lh[t] = hb[t];
  lh[t + 1024] = hb[t + 1024];

  constexpr float INV2PI = 0.15915494309189535f;
  constexpr float QSCALE = 0.70710678118654752f * 1.4426950408889634f;  // rs2*log2e
  float twf2[4], tbf2[4], wq[16], wkh[16], wkp[16], wvh[16], wvp[16];
#pragma unroll
  for (int j = 0; j < 4; j++) { twf2[j] = tw[j] * INV2PI; tbf2[j] = tb[j] * INV2PI; }
#pragma unroll
  for (int j = 0; j < 16; j++) wq[j] = Wq[j];
#pragma unroll
  for (int j = 0; j < 16; j++) { wkh[j] = Wk[j]; wkp[j] = Wk[16 + j]; }
#pragma unroll
  for (int j = 0; j < 16; j++) { wvh[j] = Wv[j]; wvp[j] = Wv[16 + j]; }
  __syncthreads();

  int n = half * 1024 + t;
  {
    float4 hn = lh[n];
    float q0 = (hn.x * wq[0] + hn.y * wq[4] + hn.z * wq[8]  + hn.w * wq[12]) * QSCALE;
    float q1 = (hn.x * wq[1] + hn.y * wq[5] + hn.z * wq[9]  + hn.w * wq[13]) * QSCALE;
    float q2 = (hn.x * wq[2] + hn.y * wq[6] + hn.z * wq[10] + hn.w * wq[14]) * QSCALE;
    float q3 = (hn.x * wq[3] + hn.y * wq[7] + hn.z * wq[11] + hn.w * wq[15]) * QSCALE;
    // reuse wq storage for folded logit weights
#pragma unroll
    for (int i = 0; i < 4; i++) {
      wq[i]      = q0 * wkh[i * 4 + 0] + q1 * wkh[i * 4 + 1];  // wH0: head0, h part
      wq[4 + i]  = q2 * wkh[i * 4 + 2] + q3 * wkh[i * 4 + 3];  // wH1: head1, h part
      wq[8 + i]  = q0 * wkp[i * 4 + 0] + q1 * wkp[i * 4 + 1];  // wA : head0, phi part
      wq[12 + i] = q2 * wkp[i * 4 + 2] + q3 * wkp[i * 4 + 3];  // wB : head1, phi part
    }
  }

  // flattened cursor over the 4 quarter CSR segments (absolute record index)
  int stage = 0, addr, rem, total;
  int b1, b2, b3, c1, c2, c3;
  {
    const int* rp0 = row_ptr + (size_t)(b * 4 + 0) * (N + 1);
    const int* rp1 = row_ptr + (size_t)(b * 4 + 1) * (N + 1);
    const int* rp2 = row_ptr + (size_t)(b * 4 + 2) * (N + 1);
    const int* rp3 = row_ptr + (size_t)(b * 4 + 3) * (N + 1);
    int s0 = rp0[n], e0 = rp0[n + 1];
    int s1 = rp1[n], e1 = rp1[n + 1];
    int s2 = rp2[n], e2 = rp2[n + 1];
    int s3 = rp3[n], e3 = rp3[n + 1];
    int c0 = e0 - s0; c1 = e1 - s1; c2 = e2 - s2; c3 = e3 - s3;
    total = c0 + c1 + c2 + c3;
    addr = ((b * 4 + 0) << LOG2QE) + s0; rem = c0;
    b1 = ((b * 4 + 1) << LOG2QE) + s1;
    b2 = ((b * 4 + 2) << LOG2QE) + s2;
    b3 = ((b * 4 + 3) << LOG2QE) + s3;
    while (rem <= 0 && stage < 3) {
      ++stage;
      addr = (stage == 1) ? b1 : (stage == 2) ? b2 : b3;
      rem  = (stage == 1) ? c1 : (stage == 2) ? c2 : c3;
    }
  }

#define ADV() do { ++addr; --rem;                                   \
    while (rem <= 0 && stage < 3) { ++stage;                        \
      addr = (stage == 1) ? b1 : (stage == 2) ? b2 : b3;            \
      rem  = (stage == 1) ? c1 : (stage == 2) ? c2 : c3; } } while (0)
#define HW_COS(d, s) asm("v_cos_f32 %0, %1" : "=v"(d) : "v"(s))
#define HW_EXP2(d, s) asm("v_exp_f32 %0, %1" : "=v"(d) : "v"(s))

  float sA0 = 0.f, sA1 = 0.f, aA00 = 0.f, aA01 = 0.f, aA10 = 0.f, aA11 = 0.f;
  float sB0 = 0.f, sB1 = 0.f, aB00 = 0.f, aB01 = 0.f, aB10 = 0.f, aB11 = 0.f;

  int itc = (total + 1) >> 1;
  // prefetch first pair (junk-safe: exhausted cursor reads land in ws)
  int2 rA = sorted8[addr]; ADV();
  int2 rB = sorted8[addr]; ADV();

  for (int it = 0; it < itc; ++it) {
    int2 cA = rA, cB = rB;
    rA = sorted8[addr]; ADV();
    rB = sorted8[addr]; ADV();

    bool vB = (2 * it + 1) < total;
    float dtA = __int_as_float(cA.y);
    float dtB = vB ? __int_as_float(cB.y) : 0.f;  // sanitize: no NaN downstream
    float4 hsA = lh[cA.x & (N - 1)];
    float4 hsB = lh[cB.x & (N - 1)];

    float phA0, phA1, phA2, phA3, phB0, phB1, phB2, phB3;
    HW_COS(phA0, dtA * twf2[0] + tbf2[0]);
    HW_COS(phA1, dtA * twf2[1] + tbf2[1]);
    HW_COS(phA2, dtA * twf2[2] + tbf2[2]);
    HW_COS(phA3, dtA * twf2[3] + tbf2[3]);
    HW_COS(phB0, dtB * twf2[0] + tbf2[0]);
    HW_COS(phB1, dtB * twf2[1] + tbf2[1]);
    HW_COS(phB2, dtB * twf2[2] + tbf2[2]);
    HW_COS(phB3, dtB * twf2[3] + tbf2[3]);

    float lA0 = hsA.x * wq[0] + hsA.y * wq[1] + hsA.z * wq[2]  + hsA.w * wq[3]
              + phA0 * wq[8] + phA1 * wq[9] + phA2 * wq[10] + phA3 * wq[11];
    float lA1 = hsA.x * wq[4] + hsA.y * wq[5] + hsA.z * wq[6]  + hsA.w * wq[7]
              + phA0 * wq[12] + phA1 * wq[13] + phA2 * wq[14] + phA3 * wq[15];
    float lB0 = hsB.x * wq[0] + hsB.y * wq[1] + hsB.z * wq[2]  + hsB.w * wq[3]
              + phB0 * wq[8] + phB1 * wq[9] + phB2 * wq[10] + phB3 * wq[11];
    float lB1 = hsB.x * wq[4] + hsB.y * wq[5] + hsB.z * wq[6]  + hsB.w * wq[7]
              + phB0 * wq[12] + phB1 * wq[13] + phB2 * wq[14] + phB3 * wq[15];

    float pA0, pA1, eB0, eB1;
    HW_EXP2(pA0, lA0);
    HW_EXP2(pA1, lA1);
    HW_EXP2(eB0, lB0);
    HW_EXP2(eB1, lB1);
    float pB0 = vB ? eB0 : 0.f;
    float pB1 = vB ? eB1 : 0.f;

    float vA0 = hsA.x * wvh[0] + hsA.y * wvh[4] + hsA.z * wvh[8]  + hsA.w * wvh[12]
              + phA0 * wvp[0] + phA1 * wvp[4] + phA2 * wvp[8]  + phA3 * wvp[12];
    float vA1 = hsA.x * wvh[1] + hsA.y * wvh[5] + hsA.z * wvh[9]  + hsA.w * wvh[13]
              + phA0 * wvp[1] + phA1 * wvp[5] + phA2 * wvp[9]  + phA3 * wvp[13];
    float vA2 = hsA.x * wvh[2] + hsA.y * wvh[6] + hsA.z * wvh[10] + hsA.w * wvh[14]
              + phA0 * wvp[2] + phA1 * wvp[6] + phA2 * wvp[10] + phA3 * wvp[14];
    float vA3 = hsA.x * wvh[3] + hsA.y * wvh[7] + hsA.z * wvh[11] + hsA.w * wvh[15]
              + phA0 * wvp[3] + phA1 * wvp[7] + phA2 * wvp[11] + phA3 * wvp[15];
    float vB0 = hsB.x * wvh[0] + hsB.y * wvh[4] + hsB.z * wvh[8]  + hsB.w * wvh[12]
              + phB0 * wvp[0] + phB1 * wvp[4] + phB2 * wvp[8]  + phB3 * wvp[12];
    float vB1 = hsB.x * wvh[1] + hsB.y * wvh[5] + hsB.z * wvh[9]  + hsB.w * wvh[13]
              + phB0 * wvp[1] + phB1 * wvp[5] + phB2 * wvp[9]  + phB3 * wvp[13];
    float vB2 = hsB.x * wvh[2] + hsB.y * wvh[6] + hsB.z * wvh[10] + hsB.w * wvh[14]
              + phB0 * wvp[2] + phB1 * wvp[6] + phB2 * wvp[10] + phB3 * wvp[14];
    float vB3 = hsB.x * wvh[3] + hsB.y * wvh[7] + hsB.z * wvh[11] + hsB.w * wvh[15]
              + phB0 * wvp[3] + phB1 * wvp[7] + phB2 * wvp[11] + phB3 * wvp[15];

    sA0 += pA0; aA00 += pA0 * vA0; aA01 += pA0 * vA1;
    sA1 += pA1; aA10 += pA1 * vA2; aA11 += pA1 * vA3;
    sB0 += pB0; aB00 += pB0 * vB0; aB01 += pB0 * vB1;
    sB1 += pB1; aB10 += pB1 * vB2; aB11 += pB1 * vB3;
  }
#undef ADV
#undef HW_COS
#undef HW_EXP2

  float s0v = sA0 + sB0, s1v = sA1 + sB1;
  float a00 = aA00 + aB00, a01 = aA01 + aB01;
  float a10 = aA10 + aB10, a11 = aA11 + aB11;

  float den0 = (s0v == 0.f) ? 1.f : s0v;
  float den1 = (s1v == 0.f) ? 1.f : s1v;
  float at0 = a00 / den0, at1 = a01 / den0, at2 = a10 / den1, at3 = a11 / den1;

  float wof[16], bof[4];
#pragma unroll
  for (int j = 0; j < 16; j++) wof[j] = Wo[j];
#pragma unroll
  for (int j = 0; j < 4; j++) bof[j] = bo[j];

  float4 hn = lh[n];  // re-read (LDS untouched since load) to cut live range
  float o0 = bof[0] + at0 * wof[0] + at1 * wof[4] + at2 * wof[8]  + at3 * wof[12];
  float o1 = bof[1] + at0 * wof[1] + at1 * wof[5] + at2 * wof[9]  + at3 * wof[13];
  float o2 = bof[2] + at0 * wof[2] + at1 * wof[6] + at2 * wof[10] + at3 * wof[14];
  float o3 = bof[3] + at0 * wof[3] + at1 * wof[7] + at2 * wof[11] + at3 * wof[15];
  h_out[(((size_t)b) << LOG2N) + n] =
      make_float4(fmaxf(hn.x + o0, 0.f), fmaxf(hn.y + o1, 0.f),
                  fmaxf(hn.z + o2, 0.f), fmaxf(hn.w + o3, 0.f));
}

__global__ void final_kernel(const float4* __restrict__ h,
                             const int* __restrict__ src_index, const int* __restrict__ dst_index,
                             const float* __restrict__ timestamp,
                             const float* __restrict__ tw,
                             const float* __restrict__ tb,
                             const float* __restrict__ W_lin,
                             const float* __restrict__ b_lin,
                             float* __restrict__ out) {
  int b = threadIdx.x;
  if (b >= B) return;
  float4 sx = h[(((size_t)b) << LOG2N) + src_index[b]];
  float4 dx = h[(((size_t)b) << LOG2N) + dst_index[b]];
  float ts = timestamp[b];
  float f[12];
  f[0] = sx.x; f[1] = sx.y; f[2] = sx.z; f[3] = sx.w;
  f[4] = dx.x; f[5] = dx.y; f[6] = dx.z; f[7] = dx.w;
#pragma unroll
  for (int j = 0; j < 4; j++) f[8 + j] = __cosf(ts * tw[j] + tb[j]);
#pragma unroll
  for (int c = 0; c < 2; c++) {
    float o = b_lin[c];
#pragma unroll
    for (int j = 0; j < 12; j++) o += f[j] * W_lin[j * 2 + c];
    out[b * 2 + c] = o;
  }
}

}  // namespace

extern "C" void kernel_launch(void* const* d_in, const int* in_sizes, int n_in,
                              void* d_out, int out_size, void* d_ws, size_t ws_size,
                              hipStream_t stream) {
  (void)in_sizes; (void)n_in; (void)out_size; (void)ws_size;
  const float* x         = (const float*)d_in[0];
  const int*   edge_idx  = (const int*)d_in[1];
  const float* edge_time = (const float*)d_in[2];
  const float* timestamp = (const float*)d_in[3];
  const int*   src_index = (const int*)d_in[4];
  const int*   dst_index = (const int*)d_in[5];
  const float* time_w    = (const float*)d_in[6];
  const float* time_b    = (const float*)d_in[7];
  const float* Wq        = (const float*)d_in[8];
  const float* Wk        = (const float*)d_in[9];
  const float* Wv        = (const float*)d_in[10];
  const float* Wo        = (const float*)d_in[11];
  const float* bo        = (const float*)d_in[12];
  const float* W_lin     = (const float*)d_in[13];
  const float* b_lin     = (const float*)d_in[14];

  char* ws = (char*)d_ws;
  float4* h0      = (float4*)(ws + OFF_H0);
  float4* h1      = (float4*)(ws + OFF_H1);
  int2*   sorted8 = (int2*)(ws + OFF_S8);
  int*    row_ptr = (int*)(ws + OFF_RP);

  sort_kernel<<<4 * B, 1024, 0, stream>>>(edge_idx, edge_time, timestamp, sorted8, row_ptr);

  layer_kernel<<<2 * B, 1024, 0, stream>>>((const float4*)x, h1, row_ptr, sorted8,
                                           time_w, time_b,
                                           Wq + 0 * 16, Wk + 0 * 32, Wv + 0 * 32,
                                           Wo + 0 * 16, bo + 0 * 4);
  layer_kernel<<<2 * B, 1024, 0, stream>>>(h1, h0, row_ptr, sorted8,
                                           time_w, time_b,
                                           Wq + 1 * 16, Wk + 1 * 32, Wv + 1 * 32,
                                           Wo + 1 * 16, bo + 1 * 4);

  final_kernel<<<1, 128, 0, stream>>>(h0, src_index, dst_index, timestamp, time_w, time_b,
                                      W_lin, b_lin, (float*)d_out);
}

// Round 3
// 166.724 us; speedup vs baseline: 1.0391x; 1.0391x over previous
//
#include <hip/hip_runtime.h>

namespace {

constexpr int B = 128, N = 2048, E = 32768;
constexpr int LOG2N = 11, LOG2E = 15;
constexpr int QE = E / 4;          // edges per quarter block = 8192
constexpr int LOG2QE = 13;

// ws layout (bytes)
constexpr size_t OFF_H0 = 0;                     // B*N float4 = 4 MB
constexpr size_t OFF_H1 = 4u * 1024 * 1024;      // B*N float4 = 4 MB
constexpr size_t OFF_S8 = 8u * 1024 * 1024;      // B*4 quarters * QE int2 = 32 MB
constexpr size_t OFF_RP = 40u * 1024 * 1024;     // B*4*(N+1) int ~ 4.2 MB

// One block per (batch, quarter). Builds a per-quarter CSR of (src, dt)
// records entirely in LDS, then streams it out coalesced.
// R8: edges staged ONCE into registers (statically unrolled -> no scratch);
// the scatter pass re-reads nothing from global (-48 MB total HBM/L3).
__global__ __launch_bounds__(1024) void sort_kernel(const int* __restrict__ edge_index,
                                                    const float* __restrict__ edge_time,
                                                    const float* __restrict__ timestamp,
                                                    int2* __restrict__ sorted8,
                                                    int* __restrict__ row_ptr) {
  __shared__ int  cnt[N];        // 8 KB: counts -> cursors
  __shared__ int  wsum[16];
  __shared__ int2 rec[QE];       // 64 KB: local CSR records
  int blk = blockIdx.x, b = blk >> 2, q = blk & 3, t = threadIdx.x;

  cnt[t] = 0; cnt[t + 1024] = 0;
  __syncthreads();

  const int* src_arr = edge_index + (((size_t)(2 * b)) << LOG2E) + q * QE;
  const int* dst_arr = edge_index + (((size_t)(2 * b + 1)) << LOG2E) + q * QE;
  const float* et    = edge_time + (((size_t)b) << LOG2E) + q * QE;
  float ts = timestamp[b];

  // single-pass edge staging into registers (indices all compile-time)
  int srcv[8], dstv[8]; float dtv[8];
#pragma unroll
  for (int k = 0; k < 8; ++k) {
    int e = t + k * 1024;
    srcv[k] = src_arr[e];
    dstv[k] = dst_arr[e];
    dtv[k]  = ts - et[e];
  }

  // hist
#pragma unroll
  for (int k = 0; k < 8; ++k) atomicAdd(&cnt[dstv[k]], 1);
  __syncthreads();

  // exclusive scan of 2048 counts (2 per thread): wave shuffle scan +
  // single 16-partial scan. 2 barriers total.
  int i0 = 2 * t, i1 = 2 * t + 1;
  int l0 = cnt[i0], l1 = cnt[i1];
  int sum = l0 + l1;
  int lane = t & 63, wid = t >> 6;
  int incl = sum;
#pragma unroll
  for (int d = 1; d < 64; d <<= 1) {
    int v = __shfl_up(incl, d, 64);
    if (lane >= d) incl += v;
  }
  if (lane == 63) wsum[wid] = incl;
  __syncthreads();
  if (t < 16) {
    int v = wsum[t];
    int inc = v;
#pragma unroll
    for (int d = 1; d < 16; d <<= 1) {
      int u = __shfl_up(inc, d, 16);
      if (t >= d) inc += u;
    }
    wsum[t] = inc - v;  // exclusive wave offset
  }
  __syncthreads();
  int run = wsum[wid] + (incl - sum);
  int run2 = run + l0;
  int* rp = row_ptr + (size_t)blk * (N + 1);
  rp[i0] = run;
  rp[i1] = run2;
  if (t == 1023) rp[N] = QE;
  cnt[i0] = run;   // becomes cursor
  cnt[i1] = run2;
  __syncthreads();

  // scatter into LDS CSR straight from registers
#pragma unroll
  for (int k = 0; k < 8; ++k) {
    int pos = atomicAdd(&cnt[dstv[k]], 1);
    rec[pos] = make_int2(srcv[k], __float_as_int(dtv[k]));
  }
  __syncthreads();

  // coalesced stream-out (int4 = 2 records)
  const int4* rec4 = (const int4*)rec;
  int4* out4 = (int4*)(sorted8 + (((size_t)blk) << LOG2QE));
#pragma unroll
  for (int i = t; i < QE / 2; i += 1024) out4[i] = rec4[i];
}

// R8 layer kernel. Theory: sorted8 records are single-use and written by
// other XCDs -> every record read is a ~500-cycle remote-L2/L3 hit; the
// R6/R7 1-deep prefetch (~150-cycle body) left ~350 cycles of stall per
// iteration at only 4 waves/SIMD.
//  - DEPTH-4 record pipeline: cursor addresses are data-independent, so 4
//    records rotate through named registers (static indices -> no scratch).
//    ~600 cycles of load latency covered.
//  - lh[] gather issued 1 iteration ahead (covers ~120-cycle LDS latency).
//  - 1-wide body (R7's 2-wide didn't cut issue slots: wave-max halves but
//    body doubles; and the doubled serial ADV chain hurt).
//  - no online max (validated R7: logits O(+-10), exp cannot overflow);
//    log2e*rsqrt(2) folded into q, 1/2pi folded into time weights; raw
//    v_cos_f32 / v_exp_f32.
__global__ __launch_bounds__(1024) void layer_kernel(const float4* __restrict__ h_in,
                                                     float4* __restrict__ h_out,
                                                     const int* __restrict__ row_ptr,
                                                     const int2* __restrict__ sorted8,
                                                     const float* __restrict__ tw,
                                                     const float* __restrict__ tb,
                                                     const float* __restrict__ Wq,
                                                     const float* __restrict__ Wk,
                                                     const float* __restrict__ Wv,
                                                     const float* __restrict__ Wo,
                                                     const float* __restrict__ bo) {
  __shared__ float4 lh[N];  // 32 KB
  int blk = blockIdx.x, b = blk >> 1, half = blk & 1, t = threadIdx.x;

  const float4* hb = h_in + (((size_t)b) << LOG2N);
  lh[t] = hb[t];
  lh[t + 1024] = hb[t + 1024];

  constexpr float INV2PI = 0.15915494309189535f;
  constexpr float QSCALE = 0.70710678118654752f * 1.4426950408889634f;  // rs2*log2e
  float twf2[4], tbf2[4], wq[16], wkh[16], wkp[16], wvh[16], wvp[16];
#pragma unroll
  for (int j = 0; j < 4; j++) { twf2[j] = tw[j] * INV2PI; tbf2[j] = tb[j] * INV2PI; }
#pragma unroll
  for (int j = 0; j < 16; j++) wq[j] = Wq[j];
#pragma unroll
  for (int j = 0; j < 16; j++) { wkh[j] = Wk[j]; wkp[j] = Wk[16 + j]; }
#pragma unroll
  for (int j = 0; j < 16; j++) { wvh[j] = Wv[j]; wvp[j] = Wv[16 + j]; }
  __syncthreads();

  int n = half * 1024 + t;
  {
    float4 hn = lh[n];
    float q0 = (hn.x * wq[0] + hn.y * wq[4] + hn.z * wq[8]  + hn.w * wq[12]) * QSCALE;
    float q1 = (hn.x * wq[1] + hn.y * wq[5] + hn.z * wq[9]  + hn.w * wq[13]) * QSCALE;
    float q2 = (hn.x * wq[2] + hn.y * wq[6] + hn.z * wq[10] + hn.w * wq[14]) * QSCALE;
    float q3 = (hn.x * wq[3] + hn.y * wq[7] + hn.z * wq[11] + hn.w * wq[15]) * QSCALE;
    // reuse wq storage for folded logit weights
#pragma unroll
    for (int i = 0; i < 4; i++) {
      wq[i]      = q0 * wkh[i * 4 + 0] + q1 * wkh[i * 4 + 1];  // wH0: head0, h part
      wq[4 + i]  = q2 * wkh[i * 4 + 2] + q3 * wkh[i * 4 + 3];  // wH1: head1, h part
      wq[8 + i]  = q0 * wkp[i * 4 + 0] + q1 * wkp[i * 4 + 1];  // wA : head0, phi part
      wq[12 + i] = q2 * wkp[i * 4 + 2] + q3 * wkp[i * 4 + 3];  // wB : head1, phi part
    }
  }

  // flattened cursor over the 4 quarter CSR segments (absolute record index)
  int stage = 0, addr, rem, total;
  int b1, b2, b3, c1, c2, c3;
  {
    const int* rp0 = row_ptr + (size_t)(b * 4 + 0) * (N + 1);
    const int* rp1 = row_ptr + (size_t)(b * 4 + 1) * (N + 1);
    const int* rp2 = row_ptr + (size_t)(b * 4 + 2) * (N + 1);
    const int* rp3 = row_ptr + (size_t)(b * 4 + 3) * (N + 1);
    int s0 = rp0[n], e0 = rp0[n + 1];
    int s1 = rp1[n], e1 = rp1[n + 1];
    int s2 = rp2[n], e2 = rp2[n + 1];
    int s3 = rp3[n], e3 = rp3[n + 1];
    int c0 = e0 - s0; c1 = e1 - s1; c2 = e2 - s2; c3 = e3 - s3;
    total = c0 + c1 + c2 + c3;
    addr = ((b * 4 + 0) << LOG2QE) + s0; rem = c0;
    b1 = ((b * 4 + 1) << LOG2QE) + s1;
    b2 = ((b * 4 + 2) << LOG2QE) + s2;
    b3 = ((b * 4 + 3) << LOG2QE) + s3;
    while (rem <= 0 && stage < 3) {
      ++stage;
      addr = (stage == 1) ? b1 : (stage == 2) ? b2 : b3;
      rem  = (stage == 1) ? c1 : (stage == 2) ? c2 : c3;
    }
  }

#define ADV() do { ++addr; --rem;                                   \
    while (rem <= 0 && stage < 3) { ++stage;                        \
      addr = (stage == 1) ? b1 : (stage == 2) ? b2 : b3;            \
      rem  = (stage == 1) ? c1 : (stage == 2) ? c2 : c3; } } while (0)
#define HW_COS(d, s) asm("v_cos_f32 %0, %1" : "=v"(d) : "v"(s))
#define HW_EXP2(d, s) asm("v_exp_f32 %0, %1" : "=v"(d) : "v"(s))

  float s0v = 0.f, s1v = 0.f, a00 = 0.f, a01 = 0.f, a10 = 0.f, a11 = 0.f;

  // depth-4 prologue. Junk-safety: exhausted cursors keep incrementing addr
  // past this batch's segments; worst case (b=127) reads a few records into
  // the row_ptr region of the same ws allocation -- valid memory, and junk
  // records are only ever consumed at iterations where the lane is
  // exec-masked (it >= total), so junk never reaches the accumulators.
  int2 r0 = sorted8[addr]; ADV();
  int2 r1 = sorted8[addr]; ADV();
  int2 r2 = sorted8[addr]; ADV();
  int2 r3 = sorted8[addr]; ADV();
  float4 hsN = lh[r0.x & (N - 1)];

  for (int it = 0; it < total; ++it) {
    int2 cur = r0;
    float4 hs = hsN;
    r0 = r1; r1 = r2; r2 = r3;
    r3 = sorted8[addr]; ADV();
    hsN = lh[r0.x & (N - 1)];  // gather 1 iteration ahead

    float dt = __int_as_float(cur.y);
    float ph0, ph1, ph2, ph3;
    HW_COS(ph0, dt * twf2[0] + tbf2[0]);
    HW_COS(ph1, dt * twf2[1] + tbf2[1]);
    HW_COS(ph2, dt * twf2[2] + tbf2[2]);
    HW_COS(ph3, dt * twf2[3] + tbf2[3]);

    float l0 = hs.x * wq[0] + hs.y * wq[1] + hs.z * wq[2]  + hs.w * wq[3]
             + ph0 * wq[8] + ph1 * wq[9] + ph2 * wq[10] + ph3 * wq[11];
    float l1 = hs.x * wq[4] + hs.y * wq[5] + hs.z * wq[6]  + hs.w * wq[7]
             + ph0 * wq[12] + ph1 * wq[13] + ph2 * wq[14] + ph3 * wq[15];

    float p0, p1;
    HW_EXP2(p0, l0);
    HW_EXP2(p1, l1);

    float v0 = hs.x * wvh[0] + hs.y * wvh[4] + hs.z * wvh[8]  + hs.w * wvh[12]
             + ph0 * wvp[0] + ph1 * wvp[4] + ph2 * wvp[8]  + ph3 * wvp[12];
    float v1 = hs.x * wvh[1] + hs.y * wvh[5] + hs.z * wvh[9]  + hs.w * wvh[13]
             + ph0 * wvp[1] + ph1 * wvp[5] + ph2 * wvp[9]  + ph3 * wvp[13];
    float v2 = hs.x * wvh[2] + hs.y * wvh[6] + hs.z * wvh[10] + hs.w * wvh[14]
             + ph0 * wvp[2] + ph1 * wvp[6] + ph2 * wvp[10] + ph3 * wvp[14];
    float v3 = hs.x * wvh[3] + hs.y * wvh[7] + hs.z * wvh[11] + hs.w * wvh[15]
             + ph0 * wvp[3] + ph1 * wvp[7] + ph2 * wvp[11] + ph3 * wvp[15];

    s0v += p0; a00 += p0 * v0; a01 += p0 * v1;
    s1v += p1; a10 += p1 * v2; a11 += p1 * v3;
  }
#undef ADV
#undef HW_COS
#undef HW_EXP2

  float den0 = (s0v == 0.f) ? 1.f : s0v;
  float den1 = (s1v == 0.f) ? 1.f : s1v;
  float at0 = a00 / den0, at1 = a01 / den0, at2 = a10 / den1, at3 = a11 / den1;

  float wof[16], bof[4];
#pragma unroll
  for (int j = 0; j < 16; j++) wof[j] = Wo[j];
#pragma unroll
  for (int j = 0; j < 4; j++) bof[j] = bo[j];

  float4 hn = lh[n];  // re-read (LDS untouched since load) to cut live range
  float o0 = bof[0] + at0 * wof[0] + at1 * wof[4] + at2 * wof[8]  + at3 * wof[12];
  float o1 = bof[1] + at0 * wof[1] + at1 * wof[5] + at2 * wof[9]  + at3 * wof[13];
  float o2 = bof[2] + at0 * wof[2] + at1 * wof[6] + at2 * wof[10] + at3 * wof[14];
  float o3 = bof[3] + at0 * wof[3] + at1 * wof[7] + at2 * wof[11] + at3 * wof[15];
  h_out[(((size_t)b) << LOG2N) + n] =
      make_float4(fmaxf(hn.x + o0, 0.f), fmaxf(hn.y + o1, 0.f),
                  fmaxf(hn.z + o2, 0.f), fmaxf(hn.w + o3, 0.f));
}

__global__ void final_kernel(const float4* __restrict__ h,
                             const int* __restrict__ src_index, const int* __restrict__ dst_index,
                             const float* __restrict__ timestamp,
                             const float* __restrict__ tw,
                             const float* __restrict__ tb,
                             const float* __restrict__ W_lin,
                             const float* __restrict__ b_lin,
                             float* __restrict__ out) {
  int b = threadIdx.x;
  if (b >= B) return;
  float4 sx = h[(((size_t)b) << LOG2N) + src_index[b]];
  float4 dx = h[(((size_t)b) << LOG2N) + dst_index[b]];
  float ts = timestamp[b];
  float f[12];
  f[0] = sx.x; f[1] = sx.y; f[2] = sx.z; f[3] = sx.w;
  f[4] = dx.x; f[5] = dx.y; f[6] = dx.z; f[7] = dx.w;
#pragma unroll
  for (int j = 0; j < 4; j++) f[8 + j] = __cosf(ts * tw[j] + tb[j]);
#pragma unroll
  for (int c = 0; c < 2; c++) {
    float o = b_lin[c];
#pragma unroll
    for (int j = 0; j < 12; j++) o += f[j] * W_lin[j * 2 + c];
    out[b * 2 + c] = o;
  }
}

}  // namespace

extern "C" void kernel_launch(void* const* d_in, const int* in_sizes, int n_in,
                              void* d_out, int out_size, void* d_ws, size_t ws_size,
                              hipStream_t stream) {
  (void)in_sizes; (void)n_in; (void)out_size; (void)ws_size;
  const float* x         = (const float*)d_in[0];
  const int*   edge_idx  = (const int*)d_in[1];
  const float* edge_time = (const float*)d_in[2];
  const float* timestamp = (const float*)d_in[3];
  const int*   src_index = (const int*)d_in[4];
  const int*   dst_index = (const int*)d_in[5];
  const float* time_w    = (const float*)d_in[6];
  const float* time_b    = (const float*)d_in[7];
  const float* Wq        = (const float*)d_in[8];
  const float* Wk        = (const float*)d_in[9];
  const float* Wv        = (const float*)d_in[10];
  const float* Wo        = (const float*)d_in[11];
  const float* bo        = (const float*)d_in[12];
  const float* W_lin     = (const float*)d_in[13];
  const float* b_lin     = (const float*)d_in[14];

  char* ws = (char*)d_ws;
  float4* h0      = (float4*)(ws + OFF_H0);
  float4* h1      = (float4*)(ws + OFF_H1);
  int2*   sorted8 = (int2*)(ws + OFF_S8);
  int*    row_ptr = (int*)(ws + OFF_RP);

  sort_kernel<<<4 * B, 1024, 0, stream>>>(edge_idx, edge_time, timestamp, sorted8, row_ptr);

  layer_kernel<<<2 * B, 1024, 0, stream>>>((const float4*)x, h1, row_ptr, sorted8,
                                           time_w, time_b,
                                           Wq + 0 * 16, Wk + 0 * 32, Wv + 0 * 32,
                                           Wo + 0 * 16, bo + 0 * 4);
  layer_kernel<<<2 * B, 1024, 0, stream>>>(h1, h0, row_ptr, sorted8,
                                           time_w, time_b,
                                           Wq + 1 * 16, Wk + 1 * 32, Wv + 1 * 32,
                                           Wo + 1 * 16, bo + 1 * 4);

  final_kernel<<<1, 128, 0, stream>>>(h0, src_index, dst_index, timestamp, time_w, time_b,
                                      W_lin, b_lin, (float*)d_out);
}